// Round 6
// baseline (612.773 us; speedup 1.0000x reference)
//
#include <hip/hip_runtime.h>
#include <hip/hip_bf16.h>

typedef unsigned int u32;
typedef unsigned short u16;
typedef unsigned char u8;
typedef __attribute__((ext_vector_type(8))) __bf16 bfrag;   // 8 bf16 = 4 VGPRs (MFMA A/B operand)
typedef __attribute__((ext_vector_type(4))) float f32x4;    // MFMA C/D
typedef __attribute__((ext_vector_type(2))) float f32x2;

#define T_STEPS 4
#define N_NODES 50000
#define E_EDGES 1600000
#define HID 128
#define OUT_CH 16

#define NCHUNK 128               // partition blocks per t; chunk = E/NCHUNK
#define CHUNK (E_EDGES / NCHUNK) // 12500
#define NBKT 196                 // dst buckets per t (256 nodes each: bkt = d>>8)
#define BCAP 10240               // records per bucket region (mean 8192, sigma~90 -> 22 sigma)

// ---- workspace layout (bytes); per-t arrays have 256-aligned strides ----
// All 4 timesteps' pipelines are independent (only GRU is recurrent).
// R5: CSR via bucket partition (196 buckets x 256 nodes); rank/hist/scan
// pipeline deleted (within-node order irrelevant to the gather sum).
#define H_STRIDE    6400000u     // h fp8 [N*128] u8
#define RS_STRIDE   204800u      // row_start [51200 int] (need 50001)
#define ZP_STRIDE   16384u       // z_sum padded [128*32] f32
#define CSR_STRIDE  3200000u     // csr src [E] u16

#define OFF_H     0u             // +4*H_STRIDE  = 25,600,000
#define OFF_RS    25600000u      // +4*RS_STRIDE = 26,419,200
#define OFF_ZPAD  26419200u      // +4*ZP_STRIDE = 26,484,736
#define OFF_CSR   26484736u      // +4*CSR      = 39,284,736
#define OFF_WB    39284736u      // W_gcn bf16  = 39,317,504
#define OFF_GCNT  39317504u      // gcnt [4][256] u32 = 39,321,600
#define OFF_BBASE 39321600u      // bbase [4][256] u32 = 39,325,696
#define OFF_RECS  39325696u      // recs [4][196][BCAP] u32 -> ends ~71.4 MB

__device__ __forceinline__ u8 f32_to_fp8(float v) {
    return (u8)(__builtin_amdgcn_cvt_pk_fp8_f32(v, v, 0, 0) & 0xFF);
}

// one-shot: W fp32 -> bf16 (32 KB, L1-resident for the GEMM)
__global__ void wbf_kernel(const float* __restrict__ W, __bf16* __restrict__ wb) {
    const int i = blockIdx.x * 256 + threadIdx.x;   // 16384
    wb[i] = (__bf16)W[i];
}

// h = fp8(x @ W^T + b) via MFMA 16x16x32 bf16, batched over t (blockIdx.y).
// Frag layouts (m89/m120-verified): A[m=lane&15][k=(lane>>4)*8+j],
// B[n=lane&15][k=(lane>>4)*8+j], C/D row=(lane>>4)*4+reg, col=lane&15.
__global__ __launch_bounds__(256) void gemm_mfma_kernel(const float* __restrict__ xs,
                                                        const __bf16* __restrict__ wb,
                                                        const float* __restrict__ b,
                                                        u8* __restrict__ h8_all) {
    const int lane = threadIdx.x & 63;
    const int wv   = threadIdx.x >> 6;      // 0..3 -> n-slice
    const int r16  = lane & 15;
    const int quad = lane >> 4;
    const int mb   = blockIdx.x;            // rows [16mb, 16mb+16)
    const int t    = blockIdx.y;
    const float* x = xs + (size_t)t * N_NODES * 128;
    u8* h8         = h8_all + (size_t)t * H_STRIDE;

    bfrag Bf[2][4];
#pragma unroll
    for (int nt = 0; nt < 2; ++nt) {
        const int c = wv * 32 + nt * 16 + r16;
#pragma unroll
        for (int ks = 0; ks < 4; ++ks)
            Bf[nt][ks] = *(const bfrag*)(wb + c * 128 + ks * 32 + quad * 8);
    }

    const float* xp = x + (size_t)(mb * 16 + r16) * 128 + quad * 8;
    bfrag Af[4];
#pragma unroll
    for (int ks = 0; ks < 4; ++ks) {
        const float* ap = xp + ks * 32;
#pragma unroll
        for (int j = 0; j < 8; ++j) Af[ks][j] = (__bf16)ap[j];
    }

    f32x4 acc0 = {0.f, 0.f, 0.f, 0.f};
    f32x4 acc1 = {0.f, 0.f, 0.f, 0.f};
#pragma unroll
    for (int ks = 0; ks < 4; ++ks) {
        acc0 = __builtin_amdgcn_mfma_f32_16x16x32_bf16(Af[ks], Bf[0][ks], acc0, 0, 0, 0);
        acc1 = __builtin_amdgcn_mfma_f32_16x16x32_bf16(Af[ks], Bf[1][ks], acc1, 0, 0, 0);
    }

    const int c0 = wv * 32 + r16;
    const float b0 = b[c0], b1 = b[c0 + 16];
#pragma unroll
    for (int r = 0; r < 4; ++r) {
        const size_t row = (size_t)(mb * 16 + quad * 4 + r) * 128;
        h8[row + c0]      = f32_to_fp8(acc0[r] + b0);
        h8[row + c0 + 16] = f32_to_fp8(acc1[r] + b1);
    }
}

// Bucket-partition the edge stream: record (dst&255)<<16 | src into per-bucket
// regions. Per-block LDS counts -> ONE global atomic per (block,bucket)
// reserves a contiguous slice -> each block's ~64 records per bucket land in
// consecutive slots (lines fully dirtied within one block's lifetime -- the
// R4 lesson: csr scatter failed because a line's writes spanned the whole
// kernel; here write-back ~= payload). XCD-pinned: t = (blockIdx&7)>>1.
__global__ __launch_bounds__(256) void part_kernel(const int* __restrict__ edges,
                                                   u32* __restrict__ gcnt,
                                                   u32* __restrict__ recs) {
    __shared__ u32 bh[NBKT], bc[NBKT];
    const int id  = blockIdx.x;              // 512 blocks
    const int xcd = id & 7;
    const int t   = xcd >> 1;
    const int c   = ((xcd & 1) << 6) | (id >> 3);   // chunk 0..127
    const int base = c * CHUNK;
    const int* src = edges + (size_t)t * 2 * E_EDGES;
    const int* dst = src + E_EDGES;
    u32* rt = recs + (size_t)t * NBKT * BCAP;
    const int tid = threadIdx.x;

    if (tid < NBKT) bh[tid] = 0;
    __syncthreads();
    for (int i = tid; i < CHUNK; i += 256)
        atomicAdd(&bh[dst[base + i] >> 8], 1u);
    __syncthreads();
    if (tid < NBKT) bc[tid] = atomicAdd(&gcnt[t * 256 + tid], bh[tid]);
    __syncthreads();
    for (int i = tid; i < CHUNK; i += 256) {
        const int d = dst[base + i];
        const int s = src[base + i];
        const int bkt = d >> 8;
        const u32 idx = atomicAdd(&bc[bkt], 1u);
        if (idx < (u32)BCAP)
            rt[(size_t)bkt * BCAP + idx] = ((u32)(d & 255) << 16) | (u32)s;
    }
}

// Exclusive prefix over the 196 bucket counts per t -> bucket bases.
__global__ __launch_bounds__(256) void bscan_kernel(const u32* __restrict__ gcnt,
                                                    u32* __restrict__ bbase) {
    __shared__ u32 sc[256];
    const int tid = threadIdx.x;
    for (int t = 0; t < T_STEPS; ++t) {
        u32 v = (tid < NBKT) ? min(gcnt[t * 256 + tid], (u32)BCAP) : 0u;
        const u32 mine = v;
        sc[tid] = v;
        __syncthreads();
        for (int d = 1; d < 256; d <<= 1) {
            const u32 u = (tid >= d) ? sc[tid - d] : 0u;
            __syncthreads();
            sc[tid] += u;
            __syncthreads();
        }
        if (tid < NBKT) bbase[t * 256 + tid] = sc[tid] - mine;
        __syncthreads();
    }
}

// One block per (t,bucket): LDS histogram over the bucket's 256 nodes, LDS
// scan, LDS scatter into a dense csr segment, coalesced write-out + row_start.
// All scattered stores hit LDS; global writes are dense (payload-only).
__global__ __launch_bounds__(256) void build_kernel(const u32* __restrict__ recs,
                                                    const u32* __restrict__ gcnt,
                                                    const u32* __restrict__ bbase,
                                                    int* __restrict__ rs_all,
                                                    u16* __restrict__ csr_all) {
    __shared__ u32 ncnt[256];
    __shared__ u32 ncur[256];
    __shared__ u16 cl[BCAP];                 // 20 KB
    const int id  = blockIdx.x;              // 784 blocks = 8 xcd * 98
    const int xcd = id & 7;
    const int t   = xcd >> 1;
    const int b   = ((xcd & 1) ? 98 : 0) + (id >> 3);   // bucket 0..195
    const int tid = threadIdx.x;
    const u32 cnt   = min(gcnt[t * 256 + b], (u32)BCAP);
    const u32 rbase = bbase[t * 256 + b];
    const u32* rp = recs + ((size_t)t * NBKT + b) * BCAP;
    int* rs  = rs_all + (size_t)t * (RS_STRIDE / 4);
    u16* csr = csr_all + (size_t)t * (CSR_STRIDE / 2);

    ncnt[tid] = 0;
    __syncthreads();
    for (u32 i = tid; i < cnt; i += 256)
        atomicAdd(&ncnt[rp[i] >> 16], 1u);
    __syncthreads();
    const u32 mine = ncnt[tid];
    for (int d = 1; d < 256; d <<= 1) {      // inclusive scan
        const u32 v = (tid >= d) ? ncnt[tid - d] : 0u;
        __syncthreads();
        ncnt[tid] += v;
        __syncthreads();
    }
    const u32 off = ncnt[tid] - mine;        // exclusive
    ncur[tid] = off;
    const int n = b * 256 + tid;
    if (n <= N_NODES) rs[n] = (int)(rbase + off);   // rs[50000]=E via b=195
    __syncthreads();
    for (u32 i = tid; i < cnt; i += 256) {
        const u32 r = rp[i];
        const u32 p = atomicAdd(&ncur[r >> 16], 1u);
        cl[p] = (u16)(r & 0xFFFFu);
    }
    __syncthreads();
    for (u32 i = tid; i < cnt; i += 256)
        csr[rbase + i] = cl[i];
}

// R6: channel-split gather. XCD pair per t (validated R3); within the pair,
// xcd&1 selects the 64B HALF-ROW (channels [0,64) vs [64,128)) -- each XCD's
// h8 footprint is 3.2 MB -> L2-resident (the R5 counters showed 165 MB FETCH
// = L2 thrash from both XCDs streaming the full 6.4 MB). ReLU stays correct:
// each (node,channel) sum is complete within one XCD. Lane layout: 4
// quarter-waves process 4 edges/step, lane qh=lane&15 holds 4 channels;
// 16-edge main loop keeps 4 independent h8 loads in flight (R7 lesson).
__global__ __launch_bounds__(256) void gather_kernel(const u32* __restrict__ h8_all,
                                                     const int* __restrict__ rs_all,
                                                     const u16* __restrict__ csr_all,
                                                     float* __restrict__ zp_all) {
    const int lane = threadIdx.x & 63;
    const int wv   = __builtin_amdgcn_readfirstlane((int)(threadIdx.x >> 6));
    const int qh   = lane & 15;              // dword within the 64B half-row
    const int quar = lane >> 4;              // 0..3 edge slot
    const int id   = blockIdx.x;             // 8192 blocks total
    const int xcd  = id & 7;
    const int t    = xcd >> 1;
    const int half = xcd & 1;                // channel half owned by this XCD
    const int kb   = id >> 3;                // 0..1023 within (t,half)
    const u32* h8d = h8_all + (size_t)t * (H_STRIDE / 4) + half * 16;
    const int* row_start = rs_all + (size_t)t * (RS_STRIDE / 4);
    const u16* csr = csr_all + (size_t)t * (CSR_STRIDE / 2);
    float* z_pad = zp_all + (size_t)t * (ZP_STRIDE / 4);
    const int gw   = kb * 4 + wv;
    const int nw   = 1024 * 4;              // waves per (t,half)

    float z0 = 0.f, z1 = 0.f, z2 = 0.f, z3 = 0.f;
    for (int n = gw; n < N_NODES; n += nw) {
        const int rs  = row_start[n];
        const int cnt = row_start[n + 1] - rs;
        // self loop: count once (quarter 0 only)
        const u32 us = h8d[n * 32 + qh];
        const f32x2 slo = __builtin_amdgcn_cvt_pk_f32_fp8(us, 0);
        const f32x2 shi = __builtin_amdgcn_cvt_pk_f32_fp8(us, 1);
        const bool q0 = (quar == 0);
        float a0 = q0 ? slo.x : 0.f;
        float a1 = q0 ? slo.y : 0.f;
        float a2 = q0 ? shi.x : 0.f;
        float a3 = q0 ? shi.y : 0.f;

        const u16* lst = csr + rs;
        int i = 0;
        for (; i + 16 <= cnt; i += 16) {     // 4 independent loads in flight
            const int s0 = lst[i + 0  + quar];
            const int s1 = lst[i + 4  + quar];
            const int s2 = lst[i + 8  + quar];
            const int s3 = lst[i + 12 + quar];
            const u32 u0 = h8d[s0 * 32 + qh];
            const u32 u1 = h8d[s1 * 32 + qh];
            const u32 u2 = h8d[s2 * 32 + qh];
            const u32 u3 = h8d[s3 * 32 + qh];
            const f32x2 l0 = __builtin_amdgcn_cvt_pk_f32_fp8(u0, 0);
            const f32x2 g0 = __builtin_amdgcn_cvt_pk_f32_fp8(u0, 1);
            const f32x2 l1 = __builtin_amdgcn_cvt_pk_f32_fp8(u1, 0);
            const f32x2 g1 = __builtin_amdgcn_cvt_pk_f32_fp8(u1, 1);
            const f32x2 l2 = __builtin_amdgcn_cvt_pk_f32_fp8(u2, 0);
            const f32x2 g2 = __builtin_amdgcn_cvt_pk_f32_fp8(u2, 1);
            const f32x2 l3 = __builtin_amdgcn_cvt_pk_f32_fp8(u3, 0);
            const f32x2 g3 = __builtin_amdgcn_cvt_pk_f32_fp8(u3, 1);
            a0 += (l0.x + l1.x) + (l2.x + l3.x);
            a1 += (l0.y + l1.y) + (l2.y + l3.y);
            a2 += (g0.x + g1.x) + (g2.x + g3.x);
            a3 += (g0.y + g1.y) + (g2.y + g3.y);
        }
        for (; i + 4 <= cnt; i += 4) {
            const int s = lst[i + quar];
            const u32 u = h8d[s * 32 + qh];
            const f32x2 lo = __builtin_amdgcn_cvt_pk_f32_fp8(u, 0);
            const f32x2 hi = __builtin_amdgcn_cvt_pk_f32_fp8(u, 1);
            a0 += lo.x; a1 += lo.y; a2 += hi.x; a3 += hi.y;
        }
        if (quar < cnt - i) {                // remainder 0..3 edges
            const int s = lst[i + quar];
            const u32 u = h8d[s * 32 + qh];
            const f32x2 lo = __builtin_amdgcn_cvt_pk_f32_fp8(u, 0);
            const f32x2 hi = __builtin_amdgcn_cvt_pk_f32_fp8(u, 1);
            a0 += lo.x; a1 += lo.y; a2 += hi.x; a3 += hi.y;
        }
        // combine the 4 quarters (xor 16 then 32 -> all lanes hold totals)
        a0 += __shfl_xor(a0, 16); a0 += __shfl_xor(a0, 32);
        a1 += __shfl_xor(a1, 16); a1 += __shfl_xor(a1, 32);
        a2 += __shfl_xor(a2, 16); a2 += __shfl_xor(a2, 32);
        a3 += __shfl_xor(a3, 16); a3 += __shfl_xor(a3, 32);
        const float inv = 1.0f / (float)(cnt + 1);
        z0 += fmaxf(a0 * inv, 0.f);
        z1 += fmaxf(a1 * inv, 0.f);
        z2 += fmaxf(a2 * inv, 0.f);
        z3 += fmaxf(a3 * inv, 0.f);
    }

    __shared__ float red[4][16][4];
    if (lane < 16) {
        red[wv][lane][0] = z0;
        red[wv][lane][1] = z1;
        red[wv][lane][2] = z2;
        red[wv][lane][3] = z3;
    }
    __syncthreads();
    if (threadIdx.x < 64) {
        const int c = threadIdx.x;          // channel within the half
        const int g = c >> 2, m = c & 3;
        float s = 0.f;
#pragma unroll
        for (int w = 0; w < 4; ++w) s += red[w][g][m];
        atomicAdd(&z_pad[(half * 64 + c) * 32], s);   // 128 slots, 128B apart
    }
}

// All 4 GRU steps + classifier in one block; h lives in LDS the whole time.
__global__ __launch_bounds__(512) void gru_all_kernel(const float* __restrict__ zp_all,
                                                      const float* __restrict__ W_ih,
                                                      const float* __restrict__ W_hh,
                                                      const float* __restrict__ b_ih,
                                                      const float* __restrict__ b_hh,
                                                      const float* __restrict__ W_cls,
                                                      const float* __restrict__ b_cls,
                                                      float* __restrict__ out) {
    __shared__ float zm[128], hs[128], gi[384], gh[384];
    const int tid = threadIdx.x;
    if (tid < 128) hs[tid] = 0.f;
    for (int t = 0; t < T_STEPS; ++t) {
        if (tid < 128)
            zm[tid] = zp_all[(size_t)t * (ZP_STRIDE / 4) + tid * 32] * (1.0f / (float)N_NODES);
        __syncthreads();
        if (tid < 384) {
            float a = b_ih[tid], g = b_hh[tid];
            const float* wi = W_ih + tid * 128;
            const float* wh = W_hh + tid * 128;
#pragma unroll 8
            for (int k = 0; k < 128; ++k) {
                a = fmaf(zm[k], wi[k], a);
                g = fmaf(hs[k], wh[k], g);
            }
            gi[tid] = a;
            gh[tid] = g;
        }
        __syncthreads();
        if (tid < 128) {
            const float r  = 1.f / (1.f + expf(-(gi[tid] + gh[tid])));
            const float zg = 1.f / (1.f + expf(-(gi[128 + tid] + gh[128 + tid])));
            const float ng = tanhf(gi[256 + tid] + r * gh[256 + tid]);
            hs[tid] = (1.f - zg) * ng + zg * hs[tid];
        }
        __syncthreads();
    }
    if (tid < OUT_CH) {
        float a = b_cls[tid];
        const float* wc = W_cls + tid * 128;
#pragma unroll 8
        for (int k = 0; k < 128; ++k) a = fmaf(hs[k], wc[k], a);
        out[tid] = a;
    }
}

extern "C" void kernel_launch(void* const* d_in, const int* in_sizes, int n_in,
                              void* d_out, int out_size, void* d_ws, size_t ws_size,
                              hipStream_t stream) {
    const float* xs    = (const float*)d_in[0];
    const int*   edges = (const int*)d_in[1];
    const float* W_gcn = (const float*)d_in[2];
    const float* b_gcn = (const float*)d_in[3];
    const float* W_ih  = (const float*)d_in[4];
    const float* W_hh  = (const float*)d_in[5];
    const float* b_ih  = (const float*)d_in[6];
    const float* b_hh  = (const float*)d_in[7];
    const float* W_cls = (const float*)d_in[8];
    const float* b_cls = (const float*)d_in[9];
    float* out = (float*)d_out;

    char* ws = (char*)d_ws;
    u8*    h8        = (u8*)(ws + OFF_H);
    int*   row_start = (int*)(ws + OFF_RS);
    float* z_pad     = (float*)(ws + OFF_ZPAD);
    u16*   csr       = (u16*)(ws + OFF_CSR);
    __bf16* wb       = (__bf16*)(ws + OFF_WB);
    u32*   gcnt      = (u32*)(ws + OFF_GCNT);
    u32*   bbase     = (u32*)(ws + OFF_BBASE);
    u32*   recs      = (u32*)(ws + OFF_RECS);

    // zero z accumulators + bucket counters (ws re-poisoned 0xAA per launch)
    hipMemsetAsync(z_pad, 0, 4 * ZP_STRIDE, stream);
    hipMemsetAsync(gcnt, 0, 4096, stream);
    wbf_kernel<<<64, 256, 0, stream>>>(W_gcn, wb);

    // batched over all 4 timesteps; only the GRU is recurrent
    gemm_mfma_kernel<<<dim3(3125, T_STEPS), 256, 0, stream>>>(xs, wb, b_gcn, h8);
    part_kernel<<<NCHUNK * T_STEPS, 256, 0, stream>>>(edges, gcnt, recs);
    bscan_kernel<<<1, 256, 0, stream>>>(gcnt, bbase);
    build_kernel<<<98 * 8, 256, 0, stream>>>(recs, gcnt, bbase, row_start, csr);
    gather_kernel<<<2048 * T_STEPS, 256, 0, stream>>>((const u32*)h8, row_start, csr, z_pad);
    gru_all_kernel<<<1, 512, 0, stream>>>(z_pad, W_ih, W_hh, b_ih, b_hh,
                                          W_cls, b_cls, out);
}

// Round 7
// 562.260 us; speedup vs baseline: 1.0898x; 1.0898x over previous
//
#include <hip/hip_runtime.h>
#include <hip/hip_bf16.h>

typedef unsigned int u32;
typedef unsigned short u16;
typedef unsigned char u8;
typedef __attribute__((ext_vector_type(8))) __bf16 bfrag;   // 8 bf16 = 4 VGPRs (MFMA A/B operand)
typedef __attribute__((ext_vector_type(4))) float f32x4;    // MFMA C/D
typedef __attribute__((ext_vector_type(2))) float f32x2;

#define T_STEPS 4
#define N_NODES 50000
#define E_EDGES 1600000
#define HID 128
#define OUT_CH 16

#define NCHUNK 128               // partition blocks per t; chunk = E/NCHUNK
#define CHUNK (E_EDGES / NCHUNK) // 12500
#define NBKT 196                 // dst buckets per t (256 nodes each: bkt = d>>8)
#define BCAP 10240               // records per bucket region (mean 8163, sigma~90 -> 23 sigma)

// ---- workspace layout (bytes); per-t arrays have 256-aligned strides ----
// R7: h stored as TWO PLANES h8[t][half][N][64] (half = channels 0-63 / 64-127).
// R6 lesson: L2 lines are 128B -- intra-line channel split doubled FETCH
// (165->328 MB). Plane split gives each XCD a disjoint 3.2 MB working set
// (< 4 MB L2) with no shared lines.
#define H_STRIDE    6400000u     // per t (two 3.2 MB planes)
#define HALF_STRIDE 3200000u     // one plane [N][64] u8
#define RS_STRIDE   204800u      // row_start [51200 int] (need 50001)
#define ZP_STRIDE   16384u       // z_sum padded [128*32] f32
#define CSR_STRIDE  3200000u     // csr src [E] u16

#define OFF_H     0u             // +4*H_STRIDE  = 25,600,000
#define OFF_RS    25600000u      // +4*RS_STRIDE = 26,419,200
#define OFF_ZPAD  26419200u      // +4*ZP_STRIDE = 26,484,736
#define OFF_CSR   26484736u      // +4*CSR      = 39,284,736
#define OFF_WB    39284736u      // W_gcn bf16  = 39,317,504
#define OFF_GCNT  39317504u      // gcnt [4][256] u32 = 39,321,600
#define OFF_RECS  39321600u      // recs [4][196][BCAP] u32 -> ends ~71.4 MB

__device__ __forceinline__ u8 f32_to_fp8(float v) {
    return (u8)(__builtin_amdgcn_cvt_pk_fp8_f32(v, v, 0, 0) & 0xFF);
}

// one-shot: W fp32 -> bf16 (32 KB, L1-resident for the GEMM)
__global__ void wbf_kernel(const float* __restrict__ W, __bf16* __restrict__ wb) {
    const int i = blockIdx.x * 256 + threadIdx.x;   // 16384
    wb[i] = (__bf16)W[i];
}

// h = fp8(x @ W^T + b) via MFMA 16x16x32 bf16, batched over t (blockIdx.y).
// Epilogue writes the two channel-half planes (half = wv>>1: acc0 channel
// wv*32+r16 and acc1 channel +16 always share a half). A-loads via float4.
__global__ __launch_bounds__(256) void gemm_mfma_kernel(const float* __restrict__ xs,
                                                        const __bf16* __restrict__ wb,
                                                        const float* __restrict__ b,
                                                        u8* __restrict__ h8_all) {
    const int lane = threadIdx.x & 63;
    const int wv   = threadIdx.x >> 6;      // 0..3 -> n-slice
    const int r16  = lane & 15;
    const int quad = lane >> 4;
    const int mb   = blockIdx.x;            // rows [16mb, 16mb+16)
    const int t    = blockIdx.y;
    const float* x = xs + (size_t)t * N_NODES * 128;
    u8* h8         = h8_all + (size_t)t * H_STRIDE;

    bfrag Bf[2][4];
#pragma unroll
    for (int nt = 0; nt < 2; ++nt) {
        const int c = wv * 32 + nt * 16 + r16;
#pragma unroll
        for (int ks = 0; ks < 4; ++ks)
            Bf[nt][ks] = *(const bfrag*)(wb + c * 128 + ks * 32 + quad * 8);
    }

    const float* xp = x + (size_t)(mb * 16 + r16) * 128 + quad * 8;
    bfrag Af[4];
#pragma unroll
    for (int ks = 0; ks < 4; ++ks) {
        const float4 v0 = *(const float4*)(xp + ks * 32);
        const float4 v1 = *(const float4*)(xp + ks * 32 + 4);
        Af[ks][0] = (__bf16)v0.x; Af[ks][1] = (__bf16)v0.y;
        Af[ks][2] = (__bf16)v0.z; Af[ks][3] = (__bf16)v0.w;
        Af[ks][4] = (__bf16)v1.x; Af[ks][5] = (__bf16)v1.y;
        Af[ks][6] = (__bf16)v1.z; Af[ks][7] = (__bf16)v1.w;
    }

    f32x4 acc0 = {0.f, 0.f, 0.f, 0.f};
    f32x4 acc1 = {0.f, 0.f, 0.f, 0.f};
#pragma unroll
    for (int ks = 0; ks < 4; ++ks) {
        acc0 = __builtin_amdgcn_mfma_f32_16x16x32_bf16(Af[ks], Bf[0][ks], acc0, 0, 0, 0);
        acc1 = __builtin_amdgcn_mfma_f32_16x16x32_bf16(Af[ks], Bf[1][ks], acc1, 0, 0, 0);
    }

    const int c0   = wv * 32 + r16;
    const int half = wv >> 1;
    const int col0 = c0 - half * 64;        // 0..47
    u8* hb = h8 + half * HALF_STRIDE;
    const float b0 = b[c0], b1 = b[c0 + 16];
#pragma unroll
    for (int r = 0; r < 4; ++r) {
        const size_t row = (size_t)(mb * 16 + quad * 4 + r) * 64;
        hb[row + col0]      = f32_to_fp8(acc0[r] + b0);
        hb[row + col0 + 16] = f32_to_fp8(acc1[r] + b1);
    }
}

// Bucket-partition the edge stream: record (dst&255)<<16 | src into per-bucket
// regions. Per-block LDS counts -> ONE global atomic per (block,bucket)
// reserves a contiguous slice -> each block's ~64 records per bucket land in
// consecutive slots (R4 lesson: write-back ~= payload only if a line's writes
// arrive within one block's lifetime). XCD-pinned: t = (blockIdx&7)>>1.
__global__ __launch_bounds__(256) void part_kernel(const int* __restrict__ edges,
                                                   u32* __restrict__ gcnt,
                                                   u32* __restrict__ recs) {
    __shared__ u32 bh[NBKT], bc[NBKT];
    const int id  = blockIdx.x;              // 512 blocks
    const int xcd = id & 7;
    const int t   = xcd >> 1;
    const int c   = ((xcd & 1) << 6) | (id >> 3);   // chunk 0..127
    const int base = c * CHUNK;
    const int* src = edges + (size_t)t * 2 * E_EDGES;
    const int* dst = src + E_EDGES;
    u32* rt = recs + (size_t)t * NBKT * BCAP;
    const int tid = threadIdx.x;

    if (tid < NBKT) bh[tid] = 0;
    __syncthreads();
    for (int i = tid; i < CHUNK; i += 256)
        atomicAdd(&bh[dst[base + i] >> 8], 1u);
    __syncthreads();
    if (tid < NBKT) bc[tid] = atomicAdd(&gcnt[t * 256 + tid], bh[tid]);
    __syncthreads();
    for (int i = tid; i < CHUNK; i += 256) {
        const int d = dst[base + i];
        const int s = src[base + i];
        const int bkt = d >> 8;
        const u32 idx = atomicAdd(&bc[bkt], 1u);
        if (idx < (u32)BCAP)
            rt[(size_t)bkt * BCAP + idx] = ((u32)(d & 255) << 16) | (u32)s;
    }
}

// One block per (t,bucket): recompute the 196-bucket prefix in LDS (deletes
// the separate bscan launch), then LDS histogram over the bucket's 256 nodes,
// LDS scan, LDS scatter into a dense csr segment, coalesced write-out +
// row_start. All scattered stores hit LDS; global writes are payload-dense.
__global__ __launch_bounds__(256) void build_kernel(const u32* __restrict__ recs,
                                                    const u32* __restrict__ gcnt,
                                                    int* __restrict__ rs_all,
                                                    u16* __restrict__ csr_all) {
    __shared__ u32 ncnt[256];
    __shared__ u32 ncur[256];
    __shared__ u32 sc[256];
    __shared__ u16 cl[BCAP];                 // 20 KB
    const int id  = blockIdx.x;              // 784 blocks = 8 xcd * 98
    const int xcd = id & 7;
    const int t   = xcd >> 1;
    const int b   = ((xcd & 1) ? 98 : 0) + (id >> 3);   // bucket 0..195
    const int tid = threadIdx.x;
    const u32 cnt = min(gcnt[t * 256 + b], (u32)BCAP);
    const u32* rp = recs + ((size_t)t * NBKT + b) * BCAP;
    int* rs  = rs_all + (size_t)t * (RS_STRIDE / 4);
    u16* csr = csr_all + (size_t)t * (CSR_STRIDE / 2);

    // bucket-base prefix (was bscan_kernel)
    sc[tid] = (tid < NBKT) ? min(gcnt[t * 256 + tid], (u32)BCAP) : 0u;
    __syncthreads();
    for (int d = 1; d < 256; d <<= 1) {
        const u32 v = (tid >= d) ? sc[tid - d] : 0u;
        __syncthreads();
        sc[tid] += v;
        __syncthreads();
    }
    const u32 rbase = sc[b] - cnt;           // exclusive prefix for bucket b

    ncnt[tid] = 0;
    __syncthreads();
    for (u32 i = tid; i < cnt; i += 256)
        atomicAdd(&ncnt[rp[i] >> 16], 1u);
    __syncthreads();
    const u32 mine = ncnt[tid];
    for (int d = 1; d < 256; d <<= 1) {      // inclusive scan
        const u32 v = (tid >= d) ? ncnt[tid - d] : 0u;
        __syncthreads();
        ncnt[tid] += v;
        __syncthreads();
    }
    const u32 off = ncnt[tid] - mine;        // exclusive
    ncur[tid] = off;
    const int n = b * 256 + tid;
    if (n <= N_NODES) rs[n] = (int)(rbase + off);   // rs[50000]=E via b=195
    __syncthreads();
    for (u32 i = tid; i < cnt; i += 256) {
        const u32 r = rp[i];
        const u32 p = atomicAdd(&ncur[r >> 16], 1u);
        cl[p] = (u16)(r & 0xFFFFu);
    }
    __syncthreads();
    for (u32 i = tid; i < cnt; i += 256)
        csr[rbase + i] = cl[i];
}

// R7 gather: plane-split channels. XCD pair per t (validated R3); xcd&1
// selects the 3.2 MB plane h8[t][half][N][64] -- disjoint L2 lines (R6
// lesson: 128B lines defeat intra-line splits), footprint < 4 MB L2.
// 4 quarter-waves process 4 edges/step, lane qh=lane&15 holds 4 channels;
// 16-edge main loop keeps 4 independent 64B loads in flight (R7 lesson).
__global__ __launch_bounds__(256) void gather_kernel(const u32* __restrict__ h8_all,
                                                     const int* __restrict__ rs_all,
                                                     const u16* __restrict__ csr_all,
                                                     float* __restrict__ zp_all) {
    const int lane = threadIdx.x & 63;
    const int wv   = __builtin_amdgcn_readfirstlane((int)(threadIdx.x >> 6));
    const int qh   = lane & 15;              // dword within the 64B plane row
    const int quar = lane >> 4;              // 0..3 edge slot
    const int id   = blockIdx.x;             // 8192 blocks total
    const int xcd  = id & 7;
    const int t    = xcd >> 1;
    const int half = xcd & 1;                // channel plane owned by this XCD
    const int kb   = id >> 3;                // 0..1023 within (t,half)
    const u32* h8d = h8_all + (size_t)t * (H_STRIDE / 4) + half * (HALF_STRIDE / 4);
    const int* row_start = rs_all + (size_t)t * (RS_STRIDE / 4);
    const u16* csr = csr_all + (size_t)t * (CSR_STRIDE / 2);
    float* z_pad = zp_all + (size_t)t * (ZP_STRIDE / 4);
    const int gw   = kb * 4 + wv;
    const int nw   = 1024 * 4;              // waves per (t,half)

    float z0 = 0.f, z1 = 0.f, z2 = 0.f, z3 = 0.f;
    for (int n = gw; n < N_NODES; n += nw) {
        const int rs  = row_start[n];
        const int cnt = row_start[n + 1] - rs;
        // self loop: count once (quarter 0 only)
        const u32 us = h8d[n * 16 + qh];
        const f32x2 slo = __builtin_amdgcn_cvt_pk_f32_fp8(us, 0);
        const f32x2 shi = __builtin_amdgcn_cvt_pk_f32_fp8(us, 1);
        const bool q0 = (quar == 0);
        float a0 = q0 ? slo.x : 0.f;
        float a1 = q0 ? slo.y : 0.f;
        float a2 = q0 ? shi.x : 0.f;
        float a3 = q0 ? shi.y : 0.f;

        const u16* lst = csr + rs;
        int i = 0;
        for (; i + 16 <= cnt; i += 16) {     // 4 independent loads in flight
            const int s0 = lst[i + 0  + quar];
            const int s1 = lst[i + 4  + quar];
            const int s2 = lst[i + 8  + quar];
            const int s3 = lst[i + 12 + quar];
            const u32 u0 = h8d[s0 * 16 + qh];
            const u32 u1 = h8d[s1 * 16 + qh];
            const u32 u2 = h8d[s2 * 16 + qh];
            const u32 u3 = h8d[s3 * 16 + qh];
            const f32x2 l0 = __builtin_amdgcn_cvt_pk_f32_fp8(u0, 0);
            const f32x2 g0 = __builtin_amdgcn_cvt_pk_f32_fp8(u0, 1);
            const f32x2 l1 = __builtin_amdgcn_cvt_pk_f32_fp8(u1, 0);
            const f32x2 g1 = __builtin_amdgcn_cvt_pk_f32_fp8(u1, 1);
            const f32x2 l2 = __builtin_amdgcn_cvt_pk_f32_fp8(u2, 0);
            const f32x2 g2 = __builtin_amdgcn_cvt_pk_f32_fp8(u2, 1);
            const f32x2 l3 = __builtin_amdgcn_cvt_pk_f32_fp8(u3, 0);
            const f32x2 g3 = __builtin_amdgcn_cvt_pk_f32_fp8(u3, 1);
            a0 += (l0.x + l1.x) + (l2.x + l3.x);
            a1 += (l0.y + l1.y) + (l2.y + l3.y);
            a2 += (g0.x + g1.x) + (g2.x + g3.x);
            a3 += (g0.y + g1.y) + (g2.y + g3.y);
        }
        for (; i + 4 <= cnt; i += 4) {
            const int s = lst[i + quar];
            const u32 u = h8d[s * 16 + qh];
            const f32x2 lo = __builtin_amdgcn_cvt_pk_f32_fp8(u, 0);
            const f32x2 hi = __builtin_amdgcn_cvt_pk_f32_fp8(u, 1);
            a0 += lo.x; a1 += lo.y; a2 += hi.x; a3 += hi.y;
        }
        if (quar < cnt - i) {                // remainder 0..3 edges
            const int s = lst[i + quar];
            const u32 u = h8d[s * 16 + qh];
            const f32x2 lo = __builtin_amdgcn_cvt_pk_f32_fp8(u, 0);
            const f32x2 hi = __builtin_amdgcn_cvt_pk_f32_fp8(u, 1);
            a0 += lo.x; a1 += lo.y; a2 += hi.x; a3 += hi.y;
        }
        // combine the 4 quarters (xor 16 then 32 -> all lanes hold totals)
        a0 += __shfl_xor(a0, 16); a0 += __shfl_xor(a0, 32);
        a1 += __shfl_xor(a1, 16); a1 += __shfl_xor(a1, 32);
        a2 += __shfl_xor(a2, 16); a2 += __shfl_xor(a2, 32);
        a3 += __shfl_xor(a3, 16); a3 += __shfl_xor(a3, 32);
        const float inv = 1.0f / (float)(cnt + 1);
        z0 += fmaxf(a0 * inv, 0.f);
        z1 += fmaxf(a1 * inv, 0.f);
        z2 += fmaxf(a2 * inv, 0.f);
        z3 += fmaxf(a3 * inv, 0.f);
    }

    __shared__ float red[4][16][4];
    if (lane < 16) {
        red[wv][lane][0] = z0;
        red[wv][lane][1] = z1;
        red[wv][lane][2] = z2;
        red[wv][lane][3] = z3;
    }
    __syncthreads();
    if (threadIdx.x < 64) {
        const int c = threadIdx.x;          // channel within the half
        const int g = c >> 2, m = c & 3;
        float s = 0.f;
#pragma unroll
        for (int w = 0; w < 4; ++w) s += red[w][g][m];
        atomicAdd(&z_pad[(half * 64 + c) * 32], s);   // 128 slots, 128B apart
    }
}

// All 4 GRU steps + classifier in one block; h lives in LDS the whole time.
__global__ __launch_bounds__(512) void gru_all_kernel(const float* __restrict__ zp_all,
                                                      const float* __restrict__ W_ih,
                                                      const float* __restrict__ W_hh,
                                                      const float* __restrict__ b_ih,
                                                      const float* __restrict__ b_hh,
                                                      const float* __restrict__ W_cls,
                                                      const float* __restrict__ b_cls,
                                                      float* __restrict__ out) {
    __shared__ float zm[128], hs[128], gi[384], gh[384];
    const int tid = threadIdx.x;
    if (tid < 128) hs[tid] = 0.f;
    for (int t = 0; t < T_STEPS; ++t) {
        if (tid < 128)
            zm[tid] = zp_all[(size_t)t * (ZP_STRIDE / 4) + tid * 32] * (1.0f / (float)N_NODES);
        __syncthreads();
        if (tid < 384) {
            float a = b_ih[tid], g = b_hh[tid];
            const float* wi = W_ih + tid * 128;
            const float* wh = W_hh + tid * 128;
#pragma unroll 8
            for (int k = 0; k < 128; ++k) {
                a = fmaf(zm[k], wi[k], a);
                g = fmaf(hs[k], wh[k], g);
            }
            gi[tid] = a;
            gh[tid] = g;
        }
        __syncthreads();
        if (tid < 128) {
            const float r  = 1.f / (1.f + expf(-(gi[tid] + gh[tid])));
            const float zg = 1.f / (1.f + expf(-(gi[128 + tid] + gh[128 + tid])));
            const float ng = tanhf(gi[256 + tid] + r * gh[256 + tid]);
            hs[tid] = (1.f - zg) * ng + zg * hs[tid];
        }
        __syncthreads();
    }
    if (tid < OUT_CH) {
        float a = b_cls[tid];
        const float* wc = W_cls + tid * 128;
#pragma unroll 8
        for (int k = 0; k < 128; ++k) a = fmaf(hs[k], wc[k], a);
        out[tid] = a;
    }
}

extern "C" void kernel_launch(void* const* d_in, const int* in_sizes, int n_in,
                              void* d_out, int out_size, void* d_ws, size_t ws_size,
                              hipStream_t stream) {
    const float* xs    = (const float*)d_in[0];
    const int*   edges = (const int*)d_in[1];
    const float* W_gcn = (const float*)d_in[2];
    const float* b_gcn = (const float*)d_in[3];
    const float* W_ih  = (const float*)d_in[4];
    const float* W_hh  = (const float*)d_in[5];
    const float* b_ih  = (const float*)d_in[6];
    const float* b_hh  = (const float*)d_in[7];
    const float* W_cls = (const float*)d_in[8];
    const float* b_cls = (const float*)d_in[9];
    float* out = (float*)d_out;

    char* ws = (char*)d_ws;
    u8*    h8        = (u8*)(ws + OFF_H);
    int*   row_start = (int*)(ws + OFF_RS);
    float* z_pad     = (float*)(ws + OFF_ZPAD);
    u16*   csr       = (u16*)(ws + OFF_CSR);
    __bf16* wb       = (__bf16*)(ws + OFF_WB);
    u32*   gcnt      = (u32*)(ws + OFF_GCNT);
    u32*   recs      = (u32*)(ws + OFF_RECS);

    // zero z accumulators + bucket counters (ws re-poisoned 0xAA per launch)
    hipMemsetAsync(z_pad, 0, 4 * ZP_STRIDE, stream);
    hipMemsetAsync(gcnt, 0, 4096, stream);
    wbf_kernel<<<64, 256, 0, stream>>>(W_gcn, wb);

    // batched over all 4 timesteps; only the GRU is recurrent
    gemm_mfma_kernel<<<dim3(3125, T_STEPS), 256, 0, stream>>>(xs, wb, b_gcn, h8);
    part_kernel<<<NCHUNK * T_STEPS, 256, 0, stream>>>(edges, gcnt, recs);
    build_kernel<<<98 * 8, 256, 0, stream>>>(recs, gcnt, row_start, csr);
    gather_kernel<<<2048 * T_STEPS, 256, 0, stream>>>((const u32*)h8, row_start, csr, z_pad);
    gru_all_kernel<<<1, 512, 0, stream>>>(z_pad, W_ih, W_hh, b_ih, b_hh,
                                          W_cls, b_cls, out);
}

// Round 8
// 553.236 us; speedup vs baseline: 1.1076x; 1.0163x over previous
//
#include <hip/hip_runtime.h>
#include <hip/hip_bf16.h>

typedef unsigned int u32;
typedef unsigned short u16;
typedef unsigned char u8;
typedef __attribute__((ext_vector_type(8))) __bf16 bfrag;   // 8 bf16 = 4 VGPRs (MFMA A/B operand)
typedef __attribute__((ext_vector_type(4))) float f32x4;    // MFMA C/D
typedef __attribute__((ext_vector_type(2))) float f32x2;

#define T_STEPS 4
#define N_NODES 50000
#define E_EDGES 1600000
#define HID 128
#define OUT_CH 16

#define NCHUNK 128               // partition blocks per t; chunk = E/NCHUNK
#define CHUNK (E_EDGES / NCHUNK) // 12500
#define NBKT 196                 // dst buckets per t (256 nodes each: bkt = d>>8)
#define BCAP 10240               // records per bucket region (mean 8163, sigma~90 -> 23 sigma)

// ---- workspace layout (bytes); per-t arrays have 256-aligned strides ----
// R7: h stored as TWO PLANES h8[t][half][N][64] (half = channels 0-63 / 64-127).
// R6 lesson: L2 lines are 128B -- intra-line channel split doubled FETCH
// (165->328 MB). Plane split gives each XCD a disjoint 3.2 MB working set
// (< 4 MB L2); R7 confirmed: gather FETCH 328->27 MB (compulsory only).
#define H_STRIDE    6400000u     // per t (two 3.2 MB planes)
#define HALF_STRIDE 3200000u     // one plane [N][64] u8
#define RS_STRIDE   204800u      // row_start [51200 int] (need 50001)
#define ZP_STRIDE   16384u       // z_sum padded [128*32] f32
#define CSR_STRIDE  3200000u     // csr src [E] u16

#define OFF_H     0u             // +4*H_STRIDE  = 25,600,000
#define OFF_RS    25600000u      // +4*RS_STRIDE = 26,419,200
#define OFF_ZPAD  26419200u      // +4*ZP_STRIDE = 26,484,736
#define OFF_CSR   26484736u      // +4*CSR      = 39,284,736
#define OFF_WB    39284736u      // W_gcn bf16  = 39,317,504
#define OFF_GCNT  39317504u      // gcnt [4][256] u32 = 39,321,600
#define OFF_RECS  39321600u      // recs [4][196][BCAP] u32 -> ends ~71.4 MB

__device__ __forceinline__ u8 f32_to_fp8(float v) {
    return (u8)(__builtin_amdgcn_cvt_pk_fp8_f32(v, v, 0, 0) & 0xFF);
}

// one-shot: W fp32 -> bf16 (32 KB, L1-resident for the GEMM)
__global__ void wbf_kernel(const float* __restrict__ W, __bf16* __restrict__ wb) {
    const int i = blockIdx.x * 256 + threadIdx.x;   // 16384
    wb[i] = (__bf16)W[i];
}

// h = fp8(x @ W^T + b) via MFMA 16x16x32 bf16, batched over t (blockIdx.y).
// Epilogue writes the two channel-half planes (half = wv>>1: acc0 channel
// wv*32+r16 and acc1 channel +16 always share a half). A-loads via float4.
__global__ __launch_bounds__(256) void gemm_mfma_kernel(const float* __restrict__ xs,
                                                        const __bf16* __restrict__ wb,
                                                        const float* __restrict__ b,
                                                        u8* __restrict__ h8_all) {
    const int lane = threadIdx.x & 63;
    const int wv   = threadIdx.x >> 6;      // 0..3 -> n-slice
    const int r16  = lane & 15;
    const int quad = lane >> 4;
    const int mb   = blockIdx.x;            // rows [16mb, 16mb+16)
    const int t    = blockIdx.y;
    const float* x = xs + (size_t)t * N_NODES * 128;
    u8* h8         = h8_all + (size_t)t * H_STRIDE;

    bfrag Bf[2][4];
#pragma unroll
    for (int nt = 0; nt < 2; ++nt) {
        const int c = wv * 32 + nt * 16 + r16;
#pragma unroll
        for (int ks = 0; ks < 4; ++ks)
            Bf[nt][ks] = *(const bfrag*)(wb + c * 128 + ks * 32 + quad * 8);
    }

    const float* xp = x + (size_t)(mb * 16 + r16) * 128 + quad * 8;
    bfrag Af[4];
#pragma unroll
    for (int ks = 0; ks < 4; ++ks) {
        const float4 v0 = *(const float4*)(xp + ks * 32);
        const float4 v1 = *(const float4*)(xp + ks * 32 + 4);
        Af[ks][0] = (__bf16)v0.x; Af[ks][1] = (__bf16)v0.y;
        Af[ks][2] = (__bf16)v0.z; Af[ks][3] = (__bf16)v0.w;
        Af[ks][4] = (__bf16)v1.x; Af[ks][5] = (__bf16)v1.y;
        Af[ks][6] = (__bf16)v1.z; Af[ks][7] = (__bf16)v1.w;
    }

    f32x4 acc0 = {0.f, 0.f, 0.f, 0.f};
    f32x4 acc1 = {0.f, 0.f, 0.f, 0.f};
#pragma unroll
    for (int ks = 0; ks < 4; ++ks) {
        acc0 = __builtin_amdgcn_mfma_f32_16x16x32_bf16(Af[ks], Bf[0][ks], acc0, 0, 0, 0);
        acc1 = __builtin_amdgcn_mfma_f32_16x16x32_bf16(Af[ks], Bf[1][ks], acc1, 0, 0, 0);
    }

    const int c0   = wv * 32 + r16;
    const int half = wv >> 1;
    const int col0 = c0 - half * 64;        // 0..47
    u8* hb = h8 + half * HALF_STRIDE;
    const float b0 = b[c0], b1 = b[c0 + 16];
#pragma unroll
    for (int r = 0; r < 4; ++r) {
        const size_t row = (size_t)(mb * 16 + quad * 4 + r) * 64;
        hb[row + col0]      = f32_to_fp8(acc0[r] + b0);
        hb[row + col0 + 16] = f32_to_fp8(acc1[r] + b1);
    }
}

// Bucket-partition the edge stream: record (dst&255)<<16 | src into per-bucket
// regions. Per-block LDS counts -> ONE global atomic per (block,bucket)
// reserves a contiguous slice -> each block's ~64 records per bucket land in
// consecutive slots (R4 lesson: write-back ~= payload only if a line's writes
// arrive within one block's lifetime). XCD-pinned: t = (blockIdx&7)>>1.
__global__ __launch_bounds__(256) void part_kernel(const int* __restrict__ edges,
                                                   u32* __restrict__ gcnt,
                                                   u32* __restrict__ recs) {
    __shared__ u32 bh[NBKT], bc[NBKT];
    const int id  = blockIdx.x;              // 512 blocks
    const int xcd = id & 7;
    const int t   = xcd >> 1;
    const int c   = ((xcd & 1) << 6) | (id >> 3);   // chunk 0..127
    const int base = c * CHUNK;
    const int* src = edges + (size_t)t * 2 * E_EDGES;
    const int* dst = src + E_EDGES;
    u32* rt = recs + (size_t)t * NBKT * BCAP;
    const int tid = threadIdx.x;

    if (tid < NBKT) bh[tid] = 0;
    __syncthreads();
    for (int i = tid; i < CHUNK; i += 256)
        atomicAdd(&bh[dst[base + i] >> 8], 1u);
    __syncthreads();
    if (tid < NBKT) bc[tid] = atomicAdd(&gcnt[t * 256 + tid], bh[tid]);
    __syncthreads();
    for (int i = tid; i < CHUNK; i += 256) {
        const int d = dst[base + i];
        const int s = src[base + i];
        const int bkt = d >> 8;
        const u32 idx = atomicAdd(&bc[bkt], 1u);
        if (idx < (u32)BCAP)
            rt[(size_t)bkt * BCAP + idx] = ((u32)(d & 255) << 16) | (u32)s;
    }
}

// One block per (t,bucket): recompute the 196-bucket prefix in LDS (deletes
// the separate bscan launch), then LDS histogram over the bucket's 256 nodes,
// LDS scan, LDS scatter into a dense csr segment, coalesced write-out +
// row_start. All scattered stores hit LDS; global writes are payload-dense.
__global__ __launch_bounds__(256) void build_kernel(const u32* __restrict__ recs,
                                                    const u32* __restrict__ gcnt,
                                                    int* __restrict__ rs_all,
                                                    u16* __restrict__ csr_all) {
    __shared__ u32 ncnt[256];
    __shared__ u32 ncur[256];
    __shared__ u32 sc[256];
    __shared__ u16 cl[BCAP];                 // 20 KB
    const int id  = blockIdx.x;              // 784 blocks = 8 xcd * 98
    const int xcd = id & 7;
    const int t   = xcd >> 1;
    const int b   = ((xcd & 1) ? 98 : 0) + (id >> 3);   // bucket 0..195
    const int tid = threadIdx.x;
    const u32 cnt = min(gcnt[t * 256 + b], (u32)BCAP);
    const u32* rp = recs + ((size_t)t * NBKT + b) * BCAP;
    int* rs  = rs_all + (size_t)t * (RS_STRIDE / 4);
    u16* csr = csr_all + (size_t)t * (CSR_STRIDE / 2);

    // bucket-base prefix (was bscan_kernel)
    sc[tid] = (tid < NBKT) ? min(gcnt[t * 256 + tid], (u32)BCAP) : 0u;
    __syncthreads();
    for (int d = 1; d < 256; d <<= 1) {
        const u32 v = (tid >= d) ? sc[tid - d] : 0u;
        __syncthreads();
        sc[tid] += v;
        __syncthreads();
    }
    const u32 rbase = sc[b] - cnt;           // exclusive prefix for bucket b

    ncnt[tid] = 0;
    __syncthreads();
    for (u32 i = tid; i < cnt; i += 256)
        atomicAdd(&ncnt[rp[i] >> 16], 1u);
    __syncthreads();
    const u32 mine = ncnt[tid];
    for (int d = 1; d < 256; d <<= 1) {      // inclusive scan
        const u32 v = (tid >= d) ? ncnt[tid - d] : 0u;
        __syncthreads();
        ncnt[tid] += v;
        __syncthreads();
    }
    const u32 off = ncnt[tid] - mine;        // exclusive
    ncur[tid] = off;
    const int n = b * 256 + tid;
    if (n <= N_NODES) rs[n] = (int)(rbase + off);   // rs[50000]=E via b=195
    __syncthreads();
    for (u32 i = tid; i < cnt; i += 256) {
        const u32 r = rp[i];
        const u32 p = atomicAdd(&ncur[r >> 16], 1u);
        cl[p] = (u16)(r & 0xFFFFu);
    }
    __syncthreads();
    for (u32 i = tid; i < cnt; i += 256)
        csr[rbase + i] = cl[i];
}

// R8 gather: plane-split (R7-validated: FETCH = compulsory) + issue-side
// rework. R7 lesson: gather is VALU/latency-bound (48% VALUBusy, dur
// unchanged when FETCH dropped 6x), NOT miss-bound. Changes:
//  - f32x2 packed accumulation (v_pk_add_f32): 16 fadd -> 8 pk_add / iter
//  - 32-edge main loop: 8 independent csr + 8 independent h8 loads in
//    flight (was 4; VGPR was 20 -> headroom)
//  - branchless predicated tail: one masked 16-edge iteration (clamp idx,
//    cndmask-zero the dword; fp8 0x00 == 0.0f) replaces 4-step loop + rem
__global__ __launch_bounds__(256) void gather_kernel(const u32* __restrict__ h8_all,
                                                     const int* __restrict__ rs_all,
                                                     const u16* __restrict__ csr_all,
                                                     float* __restrict__ zp_all) {
    const int lane = threadIdx.x & 63;
    const int wv   = __builtin_amdgcn_readfirstlane((int)(threadIdx.x >> 6));
    const int qh   = lane & 15;              // dword within the 64B plane row
    const int quar = lane >> 4;              // 0..3 edge slot
    const int id   = blockIdx.x;             // 8192 blocks total
    const int xcd  = id & 7;
    const int t    = xcd >> 1;
    const int half = xcd & 1;                // channel plane owned by this XCD
    const int kb   = id >> 3;                // 0..1023 within (t,half)
    const u32* h8d = h8_all + (size_t)t * (H_STRIDE / 4) + half * (HALF_STRIDE / 4);
    const int* row_start = rs_all + (size_t)t * (RS_STRIDE / 4);
    const u16* csr = csr_all + (size_t)t * (CSR_STRIDE / 2);
    float* z_pad = zp_all + (size_t)t * (ZP_STRIDE / 4);
    const int gw   = kb * 4 + wv;
    const int nw   = 1024 * 4;              // waves per (t,half)

    float z0 = 0.f, z1 = 0.f, z2 = 0.f, z3 = 0.f;
    for (int n = gw; n < N_NODES; n += nw) {
        const int rs  = row_start[n];
        const int cnt = row_start[n + 1] - rs;
        // self loop: count once (quarter 0 only)
        const u32 us = h8d[n * 16 + qh];
        const bool q0 = (quar == 0);
        f32x2 acc01 = q0 ? __builtin_amdgcn_cvt_pk_f32_fp8(us, 0) : (f32x2){0.f, 0.f};
        f32x2 acc23 = q0 ? __builtin_amdgcn_cvt_pk_f32_fp8(us, 1) : (f32x2){0.f, 0.f};

        const u16* lst = csr + rs;
        int i = 0;
        for (; i + 32 <= cnt; i += 32) {     // 8 independent loads in flight
            int s[8];
            u32 u[8];
#pragma unroll
            for (int k = 0; k < 8; ++k) s[k] = lst[i + k * 4 + quar];
#pragma unroll
            for (int k = 0; k < 8; ++k) u[k] = h8d[s[k] * 16 + qh];
#pragma unroll
            for (int k = 0; k < 8; ++k) {
                acc01 = acc01 + __builtin_amdgcn_cvt_pk_f32_fp8(u[k], 0);
                acc23 = acc23 + __builtin_amdgcn_cvt_pk_f32_fp8(u[k], 1);
            }
        }
        for (; i < cnt; i += 16) {           // predicated tail, branch-lean
            int s[4];
            u32 u[4];
            bool v[4];
#pragma unroll
            for (int k = 0; k < 4; ++k) {
                const int idx = i + k * 4 + quar;
                v[k] = idx < cnt;
                s[k] = lst[v[k] ? idx : 0];
            }
#pragma unroll
            for (int k = 0; k < 4; ++k) u[k] = v[k] ? h8d[s[k] * 16 + qh] : 0u;
#pragma unroll
            for (int k = 0; k < 4; ++k) {
                acc01 = acc01 + __builtin_amdgcn_cvt_pk_f32_fp8(u[k], 0);
                acc23 = acc23 + __builtin_amdgcn_cvt_pk_f32_fp8(u[k], 1);
            }
        }
        // combine the 4 quarters (xor 16 then 32 -> all lanes hold totals)
        float a0 = acc01.x, a1 = acc01.y, a2 = acc23.x, a3 = acc23.y;
        a0 += __shfl_xor(a0, 16); a0 += __shfl_xor(a0, 32);
        a1 += __shfl_xor(a1, 16); a1 += __shfl_xor(a1, 32);
        a2 += __shfl_xor(a2, 16); a2 += __shfl_xor(a2, 32);
        a3 += __shfl_xor(a3, 16); a3 += __shfl_xor(a3, 32);
        const float inv = 1.0f / (float)(cnt + 1);
        z0 += fmaxf(a0 * inv, 0.f);
        z1 += fmaxf(a1 * inv, 0.f);
        z2 += fmaxf(a2 * inv, 0.f);
        z3 += fmaxf(a3 * inv, 0.f);
    }

    __shared__ float red[4][16][4];
    if (lane < 16) {
        red[wv][lane][0] = z0;
        red[wv][lane][1] = z1;
        red[wv][lane][2] = z2;
        red[wv][lane][3] = z3;
    }
    __syncthreads();
    if (threadIdx.x < 64) {
        const int c = threadIdx.x;          // channel within the half
        const int g = c >> 2, m = c & 3;
        float s = 0.f;
#pragma unroll
        for (int w = 0; w < 4; ++w) s += red[w][g][m];
        atomicAdd(&z_pad[(half * 64 + c) * 32], s);   // 128 slots, 128B apart
    }
}

// All 4 GRU steps + classifier in one block; h lives in LDS the whole time.
__global__ __launch_bounds__(512) void gru_all_kernel(const float* __restrict__ zp_all,
                                                      const float* __restrict__ W_ih,
                                                      const float* __restrict__ W_hh,
                                                      const float* __restrict__ b_ih,
                                                      const float* __restrict__ b_hh,
                                                      const float* __restrict__ W_cls,
                                                      const float* __restrict__ b_cls,
                                                      float* __restrict__ out) {
    __shared__ float zm[128], hs[128], gi[384], gh[384];
    const int tid = threadIdx.x;
    if (tid < 128) hs[tid] = 0.f;
    for (int t = 0; t < T_STEPS; ++t) {
        if (tid < 128)
            zm[tid] = zp_all[(size_t)t * (ZP_STRIDE / 4) + tid * 32] * (1.0f / (float)N_NODES);
        __syncthreads();
        if (tid < 384) {
            float a = b_ih[tid], g = b_hh[tid];
            const float* wi = W_ih + tid * 128;
            const float* wh = W_hh + tid * 128;
#pragma unroll 8
            for (int k = 0; k < 128; ++k) {
                a = fmaf(zm[k], wi[k], a);
                g = fmaf(hs[k], wh[k], g);
            }
            gi[tid] = a;
            gh[tid] = g;
        }
        __syncthreads();
        if (tid < 128) {
            const float r  = 1.f / (1.f + expf(-(gi[tid] + gh[tid])));
            const float zg = 1.f / (1.f + expf(-(gi[128 + tid] + gh[128 + tid])));
            const float ng = tanhf(gi[256 + tid] + r * gh[256 + tid]);
            hs[tid] = (1.f - zg) * ng + zg * hs[tid];
        }
        __syncthreads();
    }
    if (tid < OUT_CH) {
        float a = b_cls[tid];
        const float* wc = W_cls + tid * 128;
#pragma unroll 8
        for (int k = 0; k < 128; ++k) a = fmaf(hs[k], wc[k], a);
        out[tid] = a;
    }
}

extern "C" void kernel_launch(void* const* d_in, const int* in_sizes, int n_in,
                              void* d_out, int out_size, void* d_ws, size_t ws_size,
                              hipStream_t stream) {
    const float* xs    = (const float*)d_in[0];
    const int*   edges = (const int*)d_in[1];
    const float* W_gcn = (const float*)d_in[2];
    const float* b_gcn = (const float*)d_in[3];
    const float* W_ih  = (const float*)d_in[4];
    const float* W_hh  = (const float*)d_in[5];
    const float* b_ih  = (const float*)d_in[6];
    const float* b_hh  = (const float*)d_in[7];
    const float* W_cls = (const float*)d_in[8];
    const float* b_cls = (const float*)d_in[9];
    float* out = (float*)d_out;

    char* ws = (char*)d_ws;
    u8*    h8        = (u8*)(ws + OFF_H);
    int*   row_start = (int*)(ws + OFF_RS);
    float* z_pad     = (float*)(ws + OFF_ZPAD);
    u16*   csr       = (u16*)(ws + OFF_CSR);
    __bf16* wb       = (__bf16*)(ws + OFF_WB);
    u32*   gcnt      = (u32*)(ws + OFF_GCNT);
    u32*   recs      = (u32*)(ws + OFF_RECS);

    // zero z accumulators + bucket counters (ws re-poisoned 0xAA per launch)
    hipMemsetAsync(z_pad, 0, 4 * ZP_STRIDE, stream);
    hipMemsetAsync(gcnt, 0, 4096, stream);
    wbf_kernel<<<64, 256, 0, stream>>>(W_gcn, wb);

    // batched over all 4 timesteps; only the GRU is recurrent
    gemm_mfma_kernel<<<dim3(3125, T_STEPS), 256, 0, stream>>>(xs, wb, b_gcn, h8);
    part_kernel<<<NCHUNK * T_STEPS, 256, 0, stream>>>(edges, gcnt, recs);
    build_kernel<<<98 * 8, 256, 0, stream>>>(recs, gcnt, row_start, csr);
    gather_kernel<<<2048 * T_STEPS, 256, 0, stream>>>((const u32*)h8, row_start, csr, z_pad);
    gru_all_kernel<<<1, 512, 0, stream>>>(z_pad, W_ih, W_hh, b_ih, b_hh,
                                          W_cls, b_cls, out);
}

// Round 9
// 538.719 us; speedup vs baseline: 1.1375x; 1.0269x over previous
//
#include <hip/hip_runtime.h>
#include <hip/hip_bf16.h>

typedef unsigned int u32;
typedef unsigned short u16;
typedef unsigned char u8;
typedef __attribute__((ext_vector_type(8))) __bf16 bfrag;   // 8 bf16 = 4 VGPRs (MFMA A/B operand)
typedef __attribute__((ext_vector_type(4))) float f32x4;    // MFMA C/D
typedef __attribute__((ext_vector_type(2))) float f32x2;

#define T_STEPS 4
#define N_NODES 50000
#define E_EDGES 1600000
#define HID 128
#define OUT_CH 16

#define NCHUNK 128               // partition blocks per t; chunk = E/NCHUNK
#define CHUNK (E_EDGES / NCHUNK) // 12500
#define NBKT 196                 // dst buckets per t (256 nodes each: bkt = d>>8)
#define BCAP 10240               // records per bucket region (mean 8163, sigma~90 -> 23 sigma)

// ---- workspace layout (bytes); per-t arrays have 256-aligned strides ----
// R7: h stored as TWO PLANES h8[t][half][N][64] (half = channels 0-63 / 64-127).
// R6 lesson: L2 lines are 128B -- intra-line channel split doubled FETCH.
// Plane split gives each XCD a disjoint 3.2 MB working set (< 4 MB L2);
// R7 confirmed: gather FETCH 328->27 MB (compulsory only).
#define H_STRIDE    6400000u     // per t (two 3.2 MB planes)
#define HALF_STRIDE 3200000u     // one plane [N][64] u8
#define RS_STRIDE   204800u      // row_start [51200 int] (need 50001)
#define ZP_STRIDE   16384u       // z_sum padded [128*32] f32
#define CSR_STRIDE  3200000u     // csr src [E] u16

#define OFF_H     0u             // +4*H_STRIDE  = 25,600,000
#define OFF_RS    25600000u      // +4*RS_STRIDE = 26,419,200
#define OFF_ZPAD  26419200u      // +4*ZP_STRIDE = 26,484,736
#define OFF_CSR   26484736u      // +4*CSR      = 39,284,736
#define OFF_WB    39284736u      // W_gcn bf16  = 39,317,504
#define OFF_GCNT  39317504u      // gcnt [4][256] u32 = 39,321,600
#define OFF_RECS  39321600u      // recs [4][196][BCAP] u32 -> ends ~71.4 MB

__device__ __forceinline__ u8 f32_to_fp8(float v) {
    return (u8)(__builtin_amdgcn_cvt_pk_fp8_f32(v, v, 0, 0) & 0xFF);
}

// one-shot: W fp32 -> bf16 (32 KB, L1-resident for the GEMM)
__global__ void wbf_kernel(const float* __restrict__ W, __bf16* __restrict__ wb) {
    const int i = blockIdx.x * 256 + threadIdx.x;   // 16384
    wb[i] = (__bf16)W[i];
}

// h = fp8(x @ W^T + b) via MFMA 16x16x32 bf16, batched over t (blockIdx.y).
// Epilogue writes the two channel-half planes (half = wv>>1). float4 A-loads.
__global__ __launch_bounds__(256) void gemm_mfma_kernel(const float* __restrict__ xs,
                                                        const __bf16* __restrict__ wb,
                                                        const float* __restrict__ b,
                                                        u8* __restrict__ h8_all) {
    const int lane = threadIdx.x & 63;
    const int wv   = threadIdx.x >> 6;      // 0..3 -> n-slice
    const int r16  = lane & 15;
    const int quad = lane >> 4;
    const int mb   = blockIdx.x;            // rows [16mb, 16mb+16)
    const int t    = blockIdx.y;
    const float* x = xs + (size_t)t * N_NODES * 128;
    u8* h8         = h8_all + (size_t)t * H_STRIDE;

    bfrag Bf[2][4];
#pragma unroll
    for (int nt = 0; nt < 2; ++nt) {
        const int c = wv * 32 + nt * 16 + r16;
#pragma unroll
        for (int ks = 0; ks < 4; ++ks)
            Bf[nt][ks] = *(const bfrag*)(wb + c * 128 + ks * 32 + quad * 8);
    }

    const float* xp = x + (size_t)(mb * 16 + r16) * 128 + quad * 8;
    bfrag Af[4];
#pragma unroll
    for (int ks = 0; ks < 4; ++ks) {
        const float4 v0 = *(const float4*)(xp + ks * 32);
        const float4 v1 = *(const float4*)(xp + ks * 32 + 4);
        Af[ks][0] = (__bf16)v0.x; Af[ks][1] = (__bf16)v0.y;
        Af[ks][2] = (__bf16)v0.z; Af[ks][3] = (__bf16)v0.w;
        Af[ks][4] = (__bf16)v1.x; Af[ks][5] = (__bf16)v1.y;
        Af[ks][6] = (__bf16)v1.z; Af[ks][7] = (__bf16)v1.w;
    }

    f32x4 acc0 = {0.f, 0.f, 0.f, 0.f};
    f32x4 acc1 = {0.f, 0.f, 0.f, 0.f};
#pragma unroll
    for (int ks = 0; ks < 4; ++ks) {
        acc0 = __builtin_amdgcn_mfma_f32_16x16x32_bf16(Af[ks], Bf[0][ks], acc0, 0, 0, 0);
        acc1 = __builtin_amdgcn_mfma_f32_16x16x32_bf16(Af[ks], Bf[1][ks], acc1, 0, 0, 0);
    }

    const int c0   = wv * 32 + r16;
    const int half = wv >> 1;
    const int col0 = c0 - half * 64;        // 0..47
    u8* hb = h8 + half * HALF_STRIDE;
    const float b0 = b[c0], b1 = b[c0 + 16];
#pragma unroll
    for (int r = 0; r < 4; ++r) {
        const size_t row = (size_t)(mb * 16 + quad * 4 + r) * 64;
        hb[row + col0]      = f32_to_fp8(acc0[r] + b0);
        hb[row + col0 + 16] = f32_to_fp8(acc1[r] + b1);
    }
}

// R9 part: LDS-staged bucket sort before write-out. R8 suspicion: phase-2's
// per-edge 4B global scatter puts one wave's 64 stores on 64 DIFFERENT 128B
// lines (~64 L2 transactions/instr + partial-line write-backs). Now: local
// prefix over bucket counts -> LDS-atomic scatter into staged[12500] ->
// coalesced write-out of bucket-contiguous runs (consecutive lanes,
// consecutive addresses; lines fully dirtied within one instr group).
// XCD-pinned: t = (blockIdx&7)>>1 (validated R3).
__global__ __launch_bounds__(256) void part_kernel(const int* __restrict__ edges,
                                                   u32* __restrict__ gcnt,
                                                   u32* __restrict__ recs) {
    __shared__ u32 bh[NBKT];                 // per-bucket count
    __shared__ u32 sc[256];                  // scan workspace
    __shared__ u32 lob[NBKT];                // local exclusive base (immutable)
    __shared__ u32 cur[NBKT];                // fill cursor
    __shared__ u32 gof[NBKT];                // reserved global base
    __shared__ u32 staged[CHUNK];            // 50 KB bucket-sorted records
    const int id  = blockIdx.x;              // 512 blocks
    const int xcd = id & 7;
    const int t   = xcd >> 1;
    const int c   = ((xcd & 1) << 6) | (id >> 3);   // chunk 0..127
    const int base = c * CHUNK;
    const int* src = edges + (size_t)t * 2 * E_EDGES;
    const int* dst = src + E_EDGES;
    u32* rt = recs + (size_t)t * NBKT * BCAP;
    const int tid = threadIdx.x;

    if (tid < NBKT) bh[tid] = 0;
    __syncthreads();
    for (int i = tid; i < CHUNK; i += 256)
        atomicAdd(&bh[dst[base + i] >> 8], 1u);
    __syncthreads();
    sc[tid] = (tid < NBKT) ? bh[tid] : 0u;   // inclusive scan over buckets
    __syncthreads();
    for (int d = 1; d < 256; d <<= 1) {
        const u32 v = (tid >= d) ? sc[tid - d] : 0u;
        __syncthreads();
        sc[tid] += v;
        __syncthreads();
    }
    if (tid < NBKT) {
        const u32 lo = sc[tid] - bh[tid];
        lob[tid] = lo;
        cur[tid] = lo;
        gof[tid] = atomicAdd(&gcnt[t * 256 + tid], bh[tid]);  // reserve slice
    }
    __syncthreads();
    for (int i = tid; i < CHUNK; i += 256) { // scatter into LDS (not global)
        const int d = dst[base + i];
        const int s = src[base + i];
        const u32 p = atomicAdd(&cur[d >> 8], 1u);
        staged[p] = ((u32)(d & 255) << 16) | (u32)s;
    }
    __syncthreads();
    for (int i = tid; i < CHUNK; i += 256) { // coalesced write-out
        int b = 0;                           // owner bucket: max b, lob[b]<=i
#pragma unroll
        for (int s = 128; s > 0; s >>= 1) {
            const int cand = b + s;
            if (cand < NBKT && lob[cand] <= (u32)i) b = cand;
        }
        const u32 gp = gof[b] + ((u32)i - lob[b]);
        if (gp < (u32)BCAP)
            rt[(size_t)b * BCAP + gp] = staged[i];
    }
}

// One block per (t,bucket): recompute the 196-bucket prefix in LDS, then LDS
// histogram over the bucket's 256 nodes, LDS scan, LDS scatter into a dense
// csr segment, coalesced write-out + row_start. Global writes payload-dense.
__global__ __launch_bounds__(256) void build_kernel(const u32* __restrict__ recs,
                                                    const u32* __restrict__ gcnt,
                                                    int* __restrict__ rs_all,
                                                    u16* __restrict__ csr_all) {
    __shared__ u32 ncnt[256];
    __shared__ u32 ncur[256];
    __shared__ u32 sc[256];
    __shared__ u16 cl[BCAP];                 // 20 KB
    const int id  = blockIdx.x;              // 784 blocks = 8 xcd * 98
    const int xcd = id & 7;
    const int t   = xcd >> 1;
    const int b   = ((xcd & 1) ? 98 : 0) + (id >> 3);   // bucket 0..195
    const int tid = threadIdx.x;
    const u32 cnt = min(gcnt[t * 256 + b], (u32)BCAP);
    const u32* rp = recs + ((size_t)t * NBKT + b) * BCAP;
    int* rs  = rs_all + (size_t)t * (RS_STRIDE / 4);
    u16* csr = csr_all + (size_t)t * (CSR_STRIDE / 2);

    // bucket-base prefix (was bscan_kernel)
    sc[tid] = (tid < NBKT) ? min(gcnt[t * 256 + tid], (u32)BCAP) : 0u;
    __syncthreads();
    for (int d = 1; d < 256; d <<= 1) {
        const u32 v = (tid >= d) ? sc[tid - d] : 0u;
        __syncthreads();
        sc[tid] += v;
        __syncthreads();
    }
    const u32 rbase = sc[b] - cnt;           // exclusive prefix for bucket b

    ncnt[tid] = 0;
    __syncthreads();
    for (u32 i = tid; i < cnt; i += 256)
        atomicAdd(&ncnt[rp[i] >> 16], 1u);
    __syncthreads();
    const u32 mine = ncnt[tid];
    for (int d = 1; d < 256; d <<= 1) {      // inclusive scan
        const u32 v = (tid >= d) ? ncnt[tid - d] : 0u;
        __syncthreads();
        ncnt[tid] += v;
        __syncthreads();
    }
    const u32 off = ncnt[tid] - mine;        // exclusive
    ncur[tid] = off;
    const int n = b * 256 + tid;
    if (n <= N_NODES) rs[n] = (int)(rbase + off);   // rs[50000]=E via b=195
    __syncthreads();
    for (u32 i = tid; i < cnt; i += 256) {
        const u32 r = rp[i];
        const u32 p = atomicAdd(&ncur[r >> 16], 1u);
        cl[p] = (u16)(r & 0xFFFFu);
    }
    __syncthreads();
    for (u32 i = tid; i < cnt; i += 256)
        csr[rbase + i] = cl[i];
}

// R9 gather: identical math/structure to R8 (plane-split, 32-edge unroll,
// packed f32x2 accum, predicated tail) but split into TWO dispatches by node
// range (nbase = 0 / 25000). Purpose: per-dispatch dur ~64 us drops below the
// hidden mid-pipeline kernels so the next profile reveals the true ranking
// of the ~426 us that never shows in top-5. Same XCD mapping -> dispatch 2
// finds its plane already L2-hot; near-zero cost.
__global__ __launch_bounds__(256) void gather_kernel(const u32* __restrict__ h8_all,
                                                     const int* __restrict__ rs_all,
                                                     const u16* __restrict__ csr_all,
                                                     float* __restrict__ zp_all,
                                                     int nbase) {
    const int lane = threadIdx.x & 63;
    const int wv   = __builtin_amdgcn_readfirstlane((int)(threadIdx.x >> 6));
    const int qh   = lane & 15;              // dword within the 64B plane row
    const int quar = lane >> 4;              // 0..3 edge slot
    const int id   = blockIdx.x;             // 4096 blocks
    const int xcd  = id & 7;
    const int t    = xcd >> 1;
    const int half = xcd & 1;                // channel plane owned by this XCD
    const int kb   = id >> 3;                // 0..511 within (t,half)
    const u32* h8d = h8_all + (size_t)t * (H_STRIDE / 4) + half * (HALF_STRIDE / 4);
    const int* row_start = rs_all + (size_t)t * (RS_STRIDE / 4);
    const u16* csr = csr_all + (size_t)t * (CSR_STRIDE / 2);
    float* z_pad = zp_all + (size_t)t * (ZP_STRIDE / 4);
    const int gw   = kb * 4 + wv;
    const int nw   = 512 * 4;               // waves per (t,half) per dispatch
    const int nend = nbase + N_NODES / 2;

    float z0 = 0.f, z1 = 0.f, z2 = 0.f, z3 = 0.f;
    for (int n = nbase + gw; n < nend; n += nw) {
        const int rs  = row_start[n];
        const int cnt = row_start[n + 1] - rs;
        // self loop: count once (quarter 0 only)
        const u32 us = h8d[n * 16 + qh];
        const bool q0 = (quar == 0);
        f32x2 acc01 = q0 ? __builtin_amdgcn_cvt_pk_f32_fp8(us, 0) : (f32x2){0.f, 0.f};
        f32x2 acc23 = q0 ? __builtin_amdgcn_cvt_pk_f32_fp8(us, 1) : (f32x2){0.f, 0.f};

        const u16* lst = csr + rs;
        int i = 0;
        for (; i + 32 <= cnt; i += 32) {     // 8 independent loads in flight
            int s[8];
            u32 u[8];
#pragma unroll
            for (int k = 0; k < 8; ++k) s[k] = lst[i + k * 4 + quar];
#pragma unroll
            for (int k = 0; k < 8; ++k) u[k] = h8d[s[k] * 16 + qh];
#pragma unroll
            for (int k = 0; k < 8; ++k) {
                acc01 = acc01 + __builtin_amdgcn_cvt_pk_f32_fp8(u[k], 0);
                acc23 = acc23 + __builtin_amdgcn_cvt_pk_f32_fp8(u[k], 1);
            }
        }
        for (; i < cnt; i += 16) {           // predicated tail, branch-lean
            int s[4];
            u32 u[4];
            bool v[4];
#pragma unroll
            for (int k = 0; k < 4; ++k) {
                const int idx = i + k * 4 + quar;
                v[k] = idx < cnt;
                s[k] = lst[v[k] ? idx : 0];
            }
#pragma unroll
            for (int k = 0; k < 4; ++k) u[k] = v[k] ? h8d[s[k] * 16 + qh] : 0u;
#pragma unroll
            for (int k = 0; k < 4; ++k) {
                acc01 = acc01 + __builtin_amdgcn_cvt_pk_f32_fp8(u[k], 0);
                acc23 = acc23 + __builtin_amdgcn_cvt_pk_f32_fp8(u[k], 1);
            }
        }
        // combine the 4 quarters (xor 16 then 32 -> all lanes hold totals)
        float a0 = acc01.x, a1 = acc01.y, a2 = acc23.x, a3 = acc23.y;
        a0 += __shfl_xor(a0, 16); a0 += __shfl_xor(a0, 32);
        a1 += __shfl_xor(a1, 16); a1 += __shfl_xor(a1, 32);
        a2 += __shfl_xor(a2, 16); a2 += __shfl_xor(a2, 32);
        a3 += __shfl_xor(a3, 16); a3 += __shfl_xor(a3, 32);
        const float inv = 1.0f / (float)(cnt + 1);
        z0 += fmaxf(a0 * inv, 0.f);
        z1 += fmaxf(a1 * inv, 0.f);
        z2 += fmaxf(a2 * inv, 0.f);
        z3 += fmaxf(a3 * inv, 0.f);
    }

    __shared__ float red[4][16][4];
    if (lane < 16) {
        red[wv][lane][0] = z0;
        red[wv][lane][1] = z1;
        red[wv][lane][2] = z2;
        red[wv][lane][3] = z3;
    }
    __syncthreads();
    if (threadIdx.x < 64) {
        const int c = threadIdx.x;          // channel within the half
        const int g = c >> 2, m = c & 3;
        float s = 0.f;
#pragma unroll
        for (int w = 0; w < 4; ++w) s += red[w][g][m];
        atomicAdd(&z_pad[(half * 64 + c) * 32], s);   // 128 slots, 128B apart
    }
}

// All 4 GRU steps + classifier in one block; h lives in LDS the whole time.
__global__ __launch_bounds__(512) void gru_all_kernel(const float* __restrict__ zp_all,
                                                      const float* __restrict__ W_ih,
                                                      const float* __restrict__ W_hh,
                                                      const float* __restrict__ b_ih,
                                                      const float* __restrict__ b_hh,
                                                      const float* __restrict__ W_cls,
                                                      const float* __restrict__ b_cls,
                                                      float* __restrict__ out) {
    __shared__ float zm[128], hs[128], gi[384], gh[384];
    const int tid = threadIdx.x;
    if (tid < 128) hs[tid] = 0.f;
    for (int t = 0; t < T_STEPS; ++t) {
        if (tid < 128)
            zm[tid] = zp_all[(size_t)t * (ZP_STRIDE / 4) + tid * 32] * (1.0f / (float)N_NODES);
        __syncthreads();
        if (tid < 384) {
            float a = b_ih[tid], g = b_hh[tid];
            const float* wi = W_ih + tid * 128;
            const float* wh = W_hh + tid * 128;
#pragma unroll 8
            for (int k = 0; k < 128; ++k) {
                a = fmaf(zm[k], wi[k], a);
                g = fmaf(hs[k], wh[k], g);
            }
            gi[tid] = a;
            gh[tid] = g;
        }
        __syncthreads();
        if (tid < 128) {
            const float r  = 1.f / (1.f + expf(-(gi[tid] + gh[tid])));
            const float zg = 1.f / (1.f + expf(-(gi[128 + tid] + gh[128 + tid])));
            const float ng = tanhf(gi[256 + tid] + r * gh[256 + tid]);
            hs[tid] = (1.f - zg) * ng + zg * hs[tid];
        }
        __syncthreads();
    }
    if (tid < OUT_CH) {
        float a = b_cls[tid];
        const float* wc = W_cls + tid * 128;
#pragma unroll 8
        for (int k = 0; k < 128; ++k) a = fmaf(hs[k], wc[k], a);
        out[tid] = a;
    }
}

extern "C" void kernel_launch(void* const* d_in, const int* in_sizes, int n_in,
                              void* d_out, int out_size, void* d_ws, size_t ws_size,
                              hipStream_t stream) {
    const float* xs    = (const float*)d_in[0];
    const int*   edges = (const int*)d_in[1];
    const float* W_gcn = (const float*)d_in[2];
    const float* b_gcn = (const float*)d_in[3];
    const float* W_ih  = (const float*)d_in[4];
    const float* W_hh  = (const float*)d_in[5];
    const float* b_ih  = (const float*)d_in[6];
    const float* b_hh  = (const float*)d_in[7];
    const float* W_cls = (const float*)d_in[8];
    const float* b_cls = (const float*)d_in[9];
    float* out = (float*)d_out;

    char* ws = (char*)d_ws;
    u8*    h8        = (u8*)(ws + OFF_H);
    int*   row_start = (int*)(ws + OFF_RS);
    float* z_pad     = (float*)(ws + OFF_ZPAD);
    u16*   csr       = (u16*)(ws + OFF_CSR);
    __bf16* wb       = (__bf16*)(ws + OFF_WB);
    u32*   gcnt      = (u32*)(ws + OFF_GCNT);
    u32*   recs      = (u32*)(ws + OFF_RECS);

    // zero z accumulators + bucket counters (ws re-poisoned 0xAA per launch)
    hipMemsetAsync(z_pad, 0, 4 * ZP_STRIDE, stream);
    hipMemsetAsync(gcnt, 0, 4096, stream);
    wbf_kernel<<<64, 256, 0, stream>>>(W_gcn, wb);

    // batched over all 4 timesteps; only the GRU is recurrent
    gemm_mfma_kernel<<<dim3(3125, T_STEPS), 256, 0, stream>>>(xs, wb, b_gcn, h8);
    part_kernel<<<NCHUNK * T_STEPS, 256, 0, stream>>>(edges, gcnt, recs);
    build_kernel<<<98 * 8, 256, 0, stream>>>(recs, gcnt, row_start, csr);
    gather_kernel<<<4096, 256, 0, stream>>>((const u32*)h8, row_start, csr, z_pad, 0);
    gather_kernel<<<4096, 256, 0, stream>>>((const u32*)h8, row_start, csr, z_pad, N_NODES / 2);
    gru_all_kernel<<<1, 512, 0, stream>>>(z_pad, W_ih, W_hh, b_ih, b_hh,
                                          W_cls, b_cls, out);
}